// Round 6
// baseline (261.449 us; speedup 1.0000x reference)
//
#include <hip/hip_runtime.h>
#include <hip/hip_cooperative_groups.h>
#include <math.h>

namespace cg = cooperative_groups;

namespace {
constexpr int kTokens = 8192;
constexpr int kHS = 4096;
constexpr float kTol = 1e-4f;
constexpr float kEps = 1e-8f;
constexpr int kMaxIters = 1000;
constexpr int kSinkBlocks = 32;  // regular launch; 32 << 256 CUs -> co-resident
constexpr int kSplit = 4;        // K-split for k_logits (grid 512)
// ws layout: [tags: 2*32 uint (padded 512B)][gdata: 2*32*64 f32]
//            [part: 128tile x 4split x 64 x 64 f32 (8MB)]
//            [whi: 512KB frag-packed bf16][wlo: 512KB]
constexpr size_t kTagFloats = 128;            // 2*32 uints used, padded
constexpr size_t kGdataFloats = 2 * 32 * 64;  // 4096
constexpr size_t kPartOff = kTagFloats + kGdataFloats;         // 4224
constexpr size_t kPartFloats = (size_t)kTokens * kSplit * 64;  // 2097152
constexpr size_t kWhiOff = kPartOff + kPartFloats;
constexpr size_t kWFragFloats = (size_t)(kHS / 32) * 4 * 64 * 4;  // 131072
constexpr size_t kWloOff = kWhiOff + kWFragFloats;
constexpr size_t kWsNeedFloats = kWloOff + kWFragFloats;
constexpr size_t kWtpFloats = (size_t)(kHS / 4) * 64 * 4;  // fallback only
}  // namespace

__device__ __forceinline__ float wave_sum(float v) {
#pragma unroll
  for (int o = 32; o; o >>= 1) v += __shfl_xor(v, o, 64);
  return v;
}

// ---------- bf16 split helpers ----------
typedef __attribute__((ext_vector_type(8))) short bf16x8;
typedef __attribute__((ext_vector_type(4))) float f32x4;

__device__ __forceinline__ unsigned short f2bf(float x) {
  unsigned u = __builtin_bit_cast(unsigned, x);
  u += 0x7fffu + ((u >> 16) & 1u);  // RNE; inputs are finite
  return (unsigned short)(u >> 16);
}

__device__ __forceinline__ void split8r(const float4 a, const float4 b,
                                        bf16x8& hi, bf16x8& lo) {
  const float v[8] = {a.x, a.y, a.z, a.w, b.x, b.y, b.z, b.w};
#pragma unroll
  for (int j = 0; j < 8; ++j) {
    const unsigned short h = f2bf(v[j]);
    const float hf = __builtin_bit_cast(float, (unsigned)h << 16);
    hi[j] = (short)h;
    lo[j] = (short)f2bf(v[j] - hf);  // exact two-term split, then RNE
  }
}

__device__ __forceinline__ void split8(const float* p, bf16x8& hi, bf16x8& lo) {
  split8r(*(const float4*)p, *(const float4*)(p + 4), hi, lo);
}

// ---------- K0: pre-convert W into fragment-packed bf16 hi/lo ----------
// Fragment (kk, n) lane l holds W[16n + (l&15)][kk*32 + (l>>4)*8 .. +8]
// (identical mapping to the verified round-1..5 B fragments).
__global__ void __launch_bounds__(256)
k_wsplit(const float* __restrict__ W, bf16x8* __restrict__ whi,
         bf16x8* __restrict__ wlo) {
  const int idx = blockIdx.x * 256 + threadIdx.x;
  const int lane = idx & 63;
  const int n = (idx >> 6) & 3;
  const int kk = idx >> 8;
  const int e = 16 * n + (lane & 15);
  const int k = kk * 32 + ((lane >> 4) << 3);
  bf16x8 hi, lo;
  split8(W + (size_t)e * kHS + k, hi, lo);
  whi[idx] = hi;
  wlo[idx] = lo;
}

// ---------- K1 v6: LDS-staged bf16-split MFMA GEMM (guide-§5 shape) ----------
// Grid 512 = 128 token-tiles x 4 K-splits; 256 thr (4 waves). Tile =
// 64 tokens x 64 experts; block covers K=1024 (32 ks-steps of 32).
// m-split: wave w owns tokens [16w,16w+16) -> no cross-wave reduce.
// Per ks: {issue next-tile global loads (T14 issue-early)} -> {compute
// current from LDS: A-read (stride-36 padded rows) + 12 MFMA} ->
// {ds_write next tile (write-late)} -> one barrier. In-flight bytes live
// in the staging pipeline (~4KB/wave issued ~full-compute-phase early),
// per Little's law for the 134MB X stream. LDS 34.8KB -> 3-4 blocks/CU.
__global__ void __launch_bounds__(256, 3)
k_logits(const float* __restrict__ X, const bf16x8* __restrict__ whi,
         const bf16x8* __restrict__ wlo, float* __restrict__ part) {
  constexpr int kXS = 36;               // padded X row stride (floats)
  constexpr int kBOffH = 64 * kXS;      // 2304
  constexpr int kBOffL = kBOffH + 1024; // 3328
  constexpr int kBufF = kBOffL + 1024;  // 4352 floats per buffer
  __shared__ __align__(16) float sm[2][kBufF];

  const int tid = threadIdx.x;
  const int lane = tid & 63;
  const int wid = tid >> 6;          // 0..3: wave owns tokens [16w,16w+16)
  const int tile = blockIdx.x >> 2;  // 0..127
  const int sig = blockIdx.x & 3;    // K slice [sig*1024, +1024)
  const int t0 = tile * 64;
  const int r15 = lane & 15;
  const int g = lane >> 4;

  // staging map (dest-linear): dest idx = p*256+tid -> row idx>>3, col (idx&7)*4
  const int srow = tid >> 3;         // 0..31 (pass 1 adds 32)
  const int scol = (tid & 7) * 4;
  const float* xsrc0 = X + (size_t)(t0 + srow) * kHS + sig * 1024 + scol;
  const float* xsrc1 = xsrc0 + (size_t)32 * kHS;
  const bf16x8* bhsrc = whi + (size_t)sig * 32 * 256 + tid;
  const bf16x8* blsrc = wlo + (size_t)sig * 32 * 256 + tid;

  f32x4 acc[4];
#pragma unroll
  for (int n = 0; n < 4; ++n) acc[n] = (f32x4){0.f, 0.f, 0.f, 0.f};

  // prologue: stage ks=0 into buf0
  {
    const float4 xv0 = *(const float4*)xsrc0;
    const float4 xv1 = *(const float4*)xsrc1;
    const bf16x8 bhv = bhsrc[0];
    const bf16x8 blv = blsrc[0];
    *(float4*)&sm[0][srow * kXS + scol] = xv0;
    *(float4*)&sm[0][(srow + 32) * kXS + scol] = xv1;
    *(bf16x8*)&sm[0][kBOffH + tid * 4] = bhv;
    *(bf16x8*)&sm[0][kBOffL + tid * 4] = blv;
  }
  __syncthreads();

  const int aoff = (16 * wid + r15) * kXS + g * 8;

#pragma unroll 2
  for (int ks = 0; ks < 32; ++ks) {
    const int cur = ks & 1;
    const bool more = (ks + 1) < 32;
    float4 xv0, xv1;
    bf16x8 bhv, blv;
    if (more) {  // issue next-tile loads EARLY (latency hides under MFMA)
      xv0 = *(const float4*)(xsrc0 + (ks + 1) * 32);
      xv1 = *(const float4*)(xsrc1 + (ks + 1) * 32);
      bhv = bhsrc[(ks + 1) * 256];
      blv = blsrc[(ks + 1) * 256];
    }
    // compute current buffer
    const float4 a0 = *(const float4*)&sm[cur][aoff];
    const float4 a1 = *(const float4*)&sm[cur][aoff + 4];
    bf16x8 ah, al;
    split8r(a0, a1, ah, al);
#pragma unroll
    for (int n = 0; n < 4; ++n) {
      const bf16x8 bh = *(const bf16x8*)&sm[cur][kBOffH + (n * 64 + lane) * 4];
      const bf16x8 bl = *(const bf16x8*)&sm[cur][kBOffL + (n * 64 + lane) * 4];
      acc[n] = __builtin_amdgcn_mfma_f32_16x16x32_bf16(ah, bh, acc[n], 0, 0, 0);
      acc[n] = __builtin_amdgcn_mfma_f32_16x16x32_bf16(al, bh, acc[n], 0, 0, 0);
      acc[n] = __builtin_amdgcn_mfma_f32_16x16x32_bf16(ah, bl, acc[n], 0, 0, 0);
    }
    if (more) {  // write-late into the other buffer
      const int nb = cur ^ 1;
      *(float4*)&sm[nb][srow * kXS + scol] = xv0;
      *(float4*)&sm[nb][(srow + 32) * kXS + scol] = xv1;
      *(bf16x8*)&sm[nb][kBOffH + tid * 4] = bhv;
      *(bf16x8*)&sm[nb][kBOffL + tid * 4] = blv;
    }
    __syncthreads();
  }

  // epilogue: C/D layout col(expert)=16n+r15, row(token)=4g+q; wave-owned
  // 16x64 sub-tile written directly (no cross-wave reduce).
  float* pb = part + ((size_t)(tile * 4 + sig) * 64 + 16 * wid) * 64;
#pragma unroll
  for (int n = 0; n < 4; ++n)
#pragma unroll
    for (int q = 0; q < 4; ++q)
      pb[(size_t)(4 * g + q) * 64 + 16 * n + r15] = acc[n][q];
}

// ---------- K2: sinkhorn + top-2 + softmax, R0-proven tag barrier ----------
// UNCHANGED from round 5 except the 3-line head index for the new part
// layout (64-token tiles x 4 K-splits).
__global__ void __launch_bounds__(1024, 1)
k_sinkhorn(const float* __restrict__ part, float* __restrict__ out,
           unsigned* __restrict__ tags, float* __restrict__ gdata) {
  const int tid = threadIdx.x;
  const int lane = tid & 63;
  const int wid = __builtin_amdgcn_readfirstlane(tid >> 6);  // 0..15
  const int blk = blockIdx.x;                                // 0..31
  __shared__ float lds[1024];

  const int t0 = blk * 256 + wid * 16;
  float lg[16], cst[16];
#pragma unroll
  for (int t = 0; t < 16; ++t) {
    const int row = t0 + t;
    const float* pb =
        part + ((size_t)(row >> 6) * 256 + (row & 63)) * 64 + lane;
    const float a = pb[0] + pb[4096] + pb[8192] + pb[12288];  // 4 K-splits
    lg[t] = a;
    cst[t] = expf(a);
  }

  // lane e holds d1[e]
  float d1 = 1.0f;
  float d0v[16];
  for (int it = 0; it < kMaxIters; ++it) {
    float p = 0.0f;
#pragma unroll
    for (int t = 0; t < 16; ++t) {
      const float s = wave_sum(d1 * cst[t]);
      const float d0t = (1.0f / 8192.0f) / (s + kEps);
      d0v[t] = d0t;
      p = fmaf(d0t, cst[t], p);
    }
    __syncthreads();
    lds[wid * 64 + lane] = p;
    __syncthreads();
    const unsigned want = (unsigned)(it + 1);
    const int buf = it & 1;
    if (wid == 0) {
      float bp = 0.0f;
#pragma unroll
      for (int w = 0; w < 16; ++w) bp += lds[w * 64 + lane];
      __hip_atomic_store(&gdata[((size_t)buf * 32 + blk) * 64 + lane], bp,
                         __ATOMIC_RELAXED, __HIP_MEMORY_SCOPE_AGENT);
      __threadfence();  // wave-wide vmcnt drain: data visible before tag
      if (lane == 0)
        __hip_atomic_store(&tags[buf * 32 + blk], want, __ATOMIC_RELEASE,
                           __HIP_MEMORY_SCOPE_AGENT);
      // poll: lane b (b<32) waits for block b's tag
      if (lane < 32) {
        while (__hip_atomic_load(&tags[buf * 32 + lane], __ATOMIC_ACQUIRE,
                                 __HIP_MEMORY_SCOPE_AGENT) != want) {
          __builtin_amdgcn_s_sleep(1);
        }
      }
    }
    __syncthreads();
    // one-shot reads; every block reduces the identical 32 values in
    // identical order -> bitwise-identical d1/err -> uniform loop exit
    float s2 = 0.0f;
#pragma unroll
    for (int i = 0; i < 2; ++i)
      s2 += __hip_atomic_load(
          &gdata[((size_t)buf * 32 + wid * 2 + i) * 64 + lane],
          __ATOMIC_RELAXED, __HIP_MEMORY_SCOPE_AGENT);
    lds[wid * 64 + lane] = s2;
    __syncthreads();
    float colsum = 0.0f;
#pragma unroll
    for (int w = 0; w < 16; ++w) colsum += lds[w * 64 + lane];
    const float d1n = (1.0f / 64.0f) / (colsum + kEps);
    const float err = wave_sum(fabsf(d1 - d1n)) * (1.0f / 64.0f);
    d1 = d1n;
    if (err <= kTol) break;
  }

  // top-2 of d1*cost*d0 + softmax scores
#pragma unroll
  for (int t = 0; t < 16; ++t) {
    const float lgv = lg[t];
    float m = lgv;
#pragma unroll
    for (int o = 32; o; o >>= 1) m = fmaxf(m, __shfl_xor(m, o, 64));
    const float ex = expf(lgv - m);
    const float den = wave_sum(ex);
    const float prob = ex / den;

    const float v = (d1 * cst[t]) * d0v[t];
    float v1 = v;
    int i1 = lane;
#pragma unroll
    for (int o = 32; o; o >>= 1) {
      const float ov = __shfl_xor(v1, o, 64);
      const int oi = __shfl_xor(i1, o, 64);
      if (ov > v1 || (ov == v1 && oi < i1)) { v1 = ov; i1 = oi; }
    }
    float v2 = (lane == i1) ? -INFINITY : v;
    int i2 = lane;
#pragma unroll
    for (int o = 32; o; o >>= 1) {
      const float ov = __shfl_xor(v2, o, 64);
      const int oi = __shfl_xor(i2, o, 64);
      if (ov > v2 || (ov == v2 && oi < i2)) { v2 = ov; i2 = oi; }
    }
    const float p1 = __shfl(prob, i1, 64);
    const float p2 = __shfl(prob, i2, 64);
    if (lane == 0) {
      const int row = t0 + t;
      out[row * 2 + 0] = p1;
      out[row * 2 + 1] = p2;
      out[2 * kTokens + row * 2 + 0] = (float)i1;
      out[2 * kTokens + row * 2 + 1] = (float)i2;
    }
  }
}

// ---------- fallback: round-1 monolithic cooperative kernel ----------
__global__ void __launch_bounds__(256, 1)
sinkhorn_router(const float* __restrict__ X, const float* __restrict__ W,
                float* __restrict__ out, float* __restrict__ ws) {
  cg::grid_group grid = cg::this_grid();
  const int tid = threadIdx.x;
  const int lane = tid & 63;
  const int wid = __builtin_amdgcn_readfirstlane(tid >> 6);
  const int blk = blockIdx.x;

  float4* wtp = reinterpret_cast<float4*>(ws);
  float* gpart = ws + kWtpFloats;
  __shared__ float lds[256];

  {
    const int j = blk * 256 + tid;
    const int e = j & 63;
    const int k4 = j >> 6;
    wtp[j] = *reinterpret_cast<const float4*>(W + (size_t)e * kHS + 4 * (size_t)k4);
  }
  grid.sync();

  const int t0 = blk * 32 + wid * 8;
  const float* xb = X + (size_t)t0 * kHS;
  float lg[8];
#pragma unroll
  for (int t = 0; t < 8; ++t) lg[t] = 0.0f;

#pragma unroll 2
  for (int k4 = 0; k4 < kHS / 4; ++k4) {
    const float4 w = wtp[k4 * 64 + lane];
#pragma unroll
    for (int t = 0; t < 8; ++t) {
      const float* xr = xb + (size_t)t * kHS + 4 * (size_t)k4;
      float a = lg[t];
      a = fmaf(xr[0], w.x, a);
      a = fmaf(xr[1], w.y, a);
      a = fmaf(xr[2], w.z, a);
      a = fmaf(xr[3], w.w, a);
      lg[t] = a;
    }
  }

  float cst[8];
#pragma unroll
  for (int t = 0; t < 8; ++t) cst[t] = expf(lg[t]);

  float d1 = 1.0f;
  float d0v[8];
  int buf = 0;
  for (int it = 0; it < kMaxIters; ++it) {
    float p = 0.0f;
#pragma unroll
    for (int t = 0; t < 8; ++t) {
      const float s = wave_sum(d1 * cst[t]);
      const float d0t = (1.0f / 8192.0f) / (s + kEps);
      d0v[t] = d0t;
      p = fmaf(d0t, cst[t], p);
    }
    __syncthreads();
    lds[wid * 64 + lane] = p;
    __syncthreads();
    if (wid == 0) {
      const float bp =
          lds[lane] + lds[64 + lane] + lds[128 + lane] + lds[192 + lane];
      gpart[buf * (256 * 64) + blk * 64 + lane] = bp;
    }
    grid.sync();
    const float* gp = gpart + buf * (256 * 64);
    float s = 0.0f;
#pragma unroll 8
    for (int b = 0; b < 64; ++b) s += gp[(wid * 64 + b) * 64 + lane];
    lds[wid * 64 + lane] = s;
    __syncthreads();
    const float colsum =
        lds[lane] + lds[64 + lane] + lds[128 + lane] + lds[192 + lane];
    const float d1n = (1.0f / 64.0f) / (colsum + kEps);
    const float err = wave_sum(fabsf(d1 - d1n)) * (1.0f / 64.0f);
    d1 = d1n;
    buf ^= 1;
    if (err <= kTol) break;
  }

#pragma unroll
  for (int t = 0; t < 8; ++t) {
    const float lgv = lg[t];
    float m = lgv;
#pragma unroll
    for (int o = 32; o; o >>= 1) m = fmaxf(m, __shfl_xor(m, o, 64));
    const float ex = expf(lgv - m);
    const float den = wave_sum(ex);
    const float prob = ex / den;

    const float v = (d1 * cst[t]) * d0v[t];
    float v1 = v;
    int i1 = lane;
#pragma unroll
    for (int o = 32; o; o >>= 1) {
      const float ov = __shfl_xor(v1, o, 64);
      const int oi = __shfl_xor(i1, o, 64);
      if (ov > v1 || (ov == v1 && oi < i1)) { v1 = ov; i1 = oi; }
    }
    float v2 = (lane == i1) ? -INFINITY : v;
    int i2 = lane;
#pragma unroll
    for (int o = 32; o; o >>= 1) {
      const float ov = __shfl_xor(v2, o, 64);
      const int oi = __shfl_xor(i2, o, 64);
      if (ov > v2 || (ov == v2 && oi < i2)) { v2 = ov; i2 = oi; }
    }
    const float p1 = __shfl(prob, i1, 64);
    const float p2 = __shfl(prob, i2, 64);
    if (lane == 0) {
      const int row = t0 + t;
      out[row * 2 + 0] = p1;
      out[row * 2 + 1] = p2;
      out[2 * kTokens + row * 2 + 0] = (float)i1;
      out[2 * kTokens + row * 2 + 1] = (float)i2;
    }
  }
}

extern "C" void kernel_launch(void* const* d_in, const int* in_sizes, int n_in,
                              void* d_out, int out_size, void* d_ws,
                              size_t ws_size, hipStream_t stream) {
  const float* X = (const float*)d_in[0];
  const float* W = (const float*)d_in[1];
  float* out = (float*)d_out;
  float* ws = (float*)d_ws;

  const size_t need = kWsNeedFloats * sizeof(float);
  if (ws_size < need) {
    void* args[] = {(void*)&X, (void*)&W, (void*)&out, (void*)&ws};
    hipLaunchCooperativeKernel((const void*)sinkhorn_router, dim3(256),
                               dim3(256), args, 0, stream);
    return;
  }

  unsigned* tags = reinterpret_cast<unsigned*>(ws);
  float* gdata = ws + kTagFloats;
  float* part = ws + kPartOff;
  bf16x8* whi = reinterpret_cast<bf16x8*>(ws + kWhiOff);
  bf16x8* wlo = reinterpret_cast<bf16x8*>(ws + kWloOff);

  // zero the tag words (ws is poisoned by the harness)
  hipMemsetAsync(tags, 0, kTagFloats * sizeof(float), stream);
  hipLaunchKernelGGL(k_wsplit, dim3((kHS / 32) * 4 * 64 / 256), dim3(256), 0,
                     stream, W, whi, wlo);
  hipLaunchKernelGGL(k_logits, dim3((kTokens / 64) * kSplit), dim3(256), 0,
                     stream, X, whi, wlo, part);
  hipLaunchKernelGGL(k_sinkhorn, dim3(kSinkBlocks), dim3(1024), 0, stream,
                     part, out, tags, gdata);
}